// Round 1
// baseline (117.956 us; speedup 1.0000x reference)
//
#include <hip/hip_runtime.h>

#define NB 4
#define NS 2048
#define ND 1024
#define NK 64

typedef __attribute__((ext_vector_type(4))) float f32x4;
typedef __attribute__((ext_vector_type(8))) short bf16x8;

__device__ __forceinline__ unsigned short f2bf(float f) {
  union { float f; unsigned int u; } v; v.f = f;
  unsigned int u = v.u;
  u += 0x7FFFu + ((u >> 16) & 1u);   // round-to-nearest-even
  return (unsigned short)(u >> 16);
}

// ---------------------------------------------------------------------------
// Kernel 0: W ([1024][64] f32, x3) -> Wt [192][1024] bf16, row = m*64+col.
// Makes MFMA B-fragments (8 consecutive d per lane) contiguous 16B loads.
// ---------------------------------------------------------------------------
__global__ __launch_bounds__(256) void wtrans_kernel(
    const float* __restrict__ Wq, const float* __restrict__ Wk,
    const float* __restrict__ Wv, unsigned short* __restrict__ Wt) {
  __shared__ float tile[64][65];
  int blk = blockIdx.x;            // 48 blocks: 3 matrices x 16 d-tiles
  int m = blk >> 4, dt = blk & 15;
  const float* W = (m == 0) ? Wq : (m == 1) ? Wk : Wv;
  int d0 = dt * 64;
  int t = threadIdx.x;
#pragma unroll
  for (int i = 0; i < 16; i++) {
    int idx = t + 256 * i;
    int dd = idx >> 6, c = idx & 63;
    tile[dd][c] = W[(d0 + dd) * 64 + c];      // coalesced read
  }
  __syncthreads();
#pragma unroll
  for (int i = 0; i < 16; i++) {
    int idx = t + 256 * i;
    int c = idx >> 6, dd = idx & 63;
    Wt[(m * 64 + c) * 1024 + d0 + dd] = f2bf(tile[dd][c]);  // coalesced write
  }
}

// ---------------------------------------------------------------------------
// Kernel 1: QKV projection. M=8192 rows, K=1024, N=192 (Q|K|V).
// 256 blocks x 256 thr: wave = (rhalf: 16 rows) x (chalf: 96 cols = 6 tiles).
// A (x, fp32->bf16) and B (Wt, bf16) fragments loaded straight from global;
// Wt is L2-resident, x rows read once (+1 L2-hit re-read by the twin wave).
// ---------------------------------------------------------------------------
__global__ __launch_bounds__(256) void qkv_kernel(
    const float* __restrict__ x, const unsigned short* __restrict__ Wt,
    const float* __restrict__ Bq, const float* __restrict__ Bk,
    const float* __restrict__ Bv,
    unsigned short* __restrict__ Qb, unsigned short* __restrict__ Kb,
    unsigned short* __restrict__ Vb) {
  int w = threadIdx.x >> 6;
  int lane = threadIdx.x & 63;
  int g = lane >> 4, c = lane & 15;
  int rhalf = w & 1, chalf = w >> 1;
  int row = blockIdx.x * 32 + rhalf * 16 + c;      // A-fragment row (lane&15)
  const float* xrow = x + (long)row * ND;
  f32x4 acc[6];
#pragma unroll
  for (int i = 0; i < 6; i++) acc[i] = (f32x4){0.f, 0.f, 0.f, 0.f};
#pragma unroll 2
  for (int ks = 0; ks < 32; ks++) {
    int d0 = ks * 32 + g * 8;                      // this lane's 8 d-slots
    f32x4 xa = *(const f32x4*)(xrow + d0);
    f32x4 xb = *(const f32x4*)(xrow + d0 + 4);
    union { bf16x8 v; unsigned short u[8]; } af;
#pragma unroll
    for (int i = 0; i < 4; i++) { af.u[i] = f2bf(xa[i]); af.u[4 + i] = f2bf(xb[i]); }
#pragma unroll
    for (int tt = 0; tt < 6; tt++) {
      int colrow = chalf * 96 + tt * 16 + c;       // B col = lane&15
      bf16x8 bf = *(const bf16x8*)&Wt[colrow * 1024 + d0];
      acc[tt] = __builtin_amdgcn_mfma_f32_16x16x32_bf16(af.v, bf, acc[tt], 0, 0, 0);
    }
  }
  // epilogue: D row = (lane>>4)*4 + reg, col = lane&15 (m89-verified)
  int orow0 = blockIdx.x * 32 + rhalf * 16 + 4 * g;
#pragma unroll
  for (int tt = 0; tt < 6; tt++) {
    int colg = chalf * 96 + tt * 16 + c;           // 0..191, never straddles 64
    int mtx = colg >> 6;
    int col = colg & 63;
    const float* Bias = (mtx == 0) ? Bq : (mtx == 1) ? Bk : Bv;
    unsigned short* Out = (mtx == 0) ? Qb : (mtx == 1) ? Kb : Vb;
#pragma unroll
    for (int j = 0; j < 4; j++) {
      int r = orow0 + j;
      float v = acc[tt][j] + Bias[(r & (NS - 1)) * NK + col];
      Out[r * NK + col] = f2bf(v);
    }
  }
}

// ---------------------------------------------------------------------------
// Kernel 2: flash attention. 256 blocks = 4 batches x 64 q-tiles(32 rows),
// 128 thr = 2 waves x 16 q-rows. K/V tiles (64 s) staged in LDS, rows padded
// to 72 bf16 (stride 144B = 16*odd -> conflict-free b128 fragment reads).
// Online softmax in registers (16-lane shfl reductions); P goes through a
// per-wave LDS buffer to convert acc-layout -> A-fragment layout.
// ---------------------------------------------------------------------------
__global__ __launch_bounds__(128) void attn_kernel(
    const unsigned short* __restrict__ Qb, const unsigned short* __restrict__ Kb,
    const unsigned short* __restrict__ Vb, float* __restrict__ out) {
  __shared__ __attribute__((aligned(16))) unsigned short Klds[64][72];
  __shared__ __attribute__((aligned(16))) unsigned short Vtlds[64][72];  // [k][s]
  __shared__ __attribute__((aligned(16))) unsigned short Plds[2][16][72];
  int w = threadIdx.x >> 6;
  int lane = threadIdx.x & 63;
  int g = lane >> 4, c = lane & 15;
  int b = blockIdx.x >> 6, qt = blockIdx.x & 63;
  long base = (long)b * NS * NK;
  int qrow = qt * 32 + w * 16;
  const float scale = 0.125f;        // 1/sqrt(64)

  bf16x8 qfrag[2];                   // Q rows stay in registers for all tiles
#pragma unroll
  for (int kk = 0; kk < 2; kk++)
    qfrag[kk] = *(const bf16x8*)&Qb[base + (qrow + c) * NK + kk * 32 + g * 8];

  f32x4 oacc[4];
#pragma unroll
  for (int i = 0; i < 4; i++) oacc[i] = (f32x4){0.f, 0.f, 0.f, 0.f};
  float mrun[4], lrun[4];
#pragma unroll
  for (int j = 0; j < 4; j++) { mrun[j] = -__builtin_inff(); lrun[j] = 0.f; }

  int tstage = threadIdx.x >> 1;             // staging: row 0..63
  int hstage = (threadIdx.x & 1) * 32;       // half-row offset

  for (int st = 0; st < 32; st++) {
    long srow = base + (long)(st * 64 + tstage) * NK;
    __syncthreads();
#pragma unroll
    for (int i = 0; i < 4; i++) {            // K: straight copy
      bf16x8 kv = *(const bf16x8*)&Kb[srow + hstage + i * 8];
      *(bf16x8*)&Klds[tstage][hstage + i * 8] = kv;
    }
#pragma unroll
    for (int i = 0; i < 4; i++) {            // V: transpose to [k][s]
      bf16x8 vv = *(const bf16x8*)&Vb[srow + hstage + i * 8];
#pragma unroll
      for (int jj = 0; jj < 8; jj++)
        Vtlds[hstage + i * 8 + jj][tstage] = (unsigned short)vv[jj];
    }
    __syncthreads();

    // S = Q K^T  (16 q-rows x 64 s per wave)
    f32x4 sacc[4];
#pragma unroll
    for (int i = 0; i < 4; i++) sacc[i] = (f32x4){0.f, 0.f, 0.f, 0.f};
#pragma unroll
    for (int tt = 0; tt < 4; tt++)
#pragma unroll
      for (int kk = 0; kk < 2; kk++) {
        bf16x8 kf = *(const bf16x8*)&Klds[tt * 16 + c][kk * 32 + g * 8];
        sacc[tt] = __builtin_amdgcn_mfma_f32_16x16x32_bf16(qfrag[kk], kf, sacc[tt], 0, 0, 0);
      }

    // online softmax: thread owns rows 4g+j across cols tt*16+c
    float p[4][4]; float alpha[4];
#pragma unroll
    for (int j = 0; j < 4; j++) {
      float v0 = fmaxf(fmaxf(sacc[0][j], sacc[1][j]), fmaxf(sacc[2][j], sacc[3][j]));
      v0 *= scale;
#pragma unroll
      for (int off = 1; off < 16; off <<= 1)
        v0 = fmaxf(v0, __shfl_xor(v0, off, 64));
      float mnew = fmaxf(mrun[j], v0);
      alpha[j] = __expf(mrun[j] - mnew);
      mrun[j] = mnew;
      float rs = 0.f;
#pragma unroll
      for (int tt = 0; tt < 4; tt++) {
        p[tt][j] = __expf(sacc[tt][j] * scale - mnew);
        rs += p[tt][j];
      }
#pragma unroll
      for (int off = 1; off < 16; off <<= 1)
        rs += __shfl_xor(rs, off, 64);
      lrun[j] = lrun[j] * alpha[j] + rs;
#pragma unroll
      for (int tt = 0; tt < 4; tt++) oacc[tt][j] *= alpha[j];
    }

    // P: acc layout -> LDS -> A-fragment layout (per-wave buffer, no barrier)
#pragma unroll
    for (int tt = 0; tt < 4; tt++)
#pragma unroll
      for (int j = 0; j < 4; j++)
        Plds[w][4 * g + j][tt * 16 + c] = f2bf(p[tt][j]);
    asm volatile("s_waitcnt lgkmcnt(0)" ::: "memory");
    bf16x8 pf[2];
#pragma unroll
    for (int kk = 0; kk < 2; kk++)
      pf[kk] = *(const bf16x8*)&Plds[w][c][kk * 32 + g * 8];

    // O += P V
#pragma unroll
    for (int tt = 0; tt < 4; tt++)
#pragma unroll
      for (int kk = 0; kk < 2; kk++) {
        bf16x8 vf = *(const bf16x8*)&Vtlds[tt * 16 + c][kk * 32 + g * 8];
        oacc[tt] = __builtin_amdgcn_mfma_f32_16x16x32_bf16(pf[kk], vf, oacc[tt], 0, 0, 0);
      }
  }

  // epilogue: out = O / l
#pragma unroll
  for (int tt = 0; tt < 4; tt++)
#pragma unroll
    for (int j = 0; j < 4; j++) {
      int q = qrow + 4 * g + j;
      out[((long)b * NS + q) * NK + tt * 16 + c] = oacc[tt][j] / lrun[j];
    }
}

// ---------------------------------------------------------------------------
extern "C" void kernel_launch(void* const* d_in, const int* in_sizes, int n_in,
                              void* d_out, int out_size, void* d_ws, size_t ws_size,
                              hipStream_t stream) {
  const float* x  = (const float*)d_in[0];
  const float* Wq = (const float*)d_in[1];
  const float* Bq = (const float*)d_in[2];
  const float* Wk = (const float*)d_in[3];
  const float* Bk = (const float*)d_in[4];
  const float* Wv = (const float*)d_in[5];
  const float* Bv = (const float*)d_in[6];
  float* out = (float*)d_out;

  // workspace layout (bytes): Wt bf16 [192][1024] | Qb | Kb | Vb  (bf16 [8192][64])
  unsigned short* Wt = (unsigned short*)d_ws;
  unsigned short* Qb = (unsigned short*)((char*)d_ws + 393216);
  unsigned short* Kb = (unsigned short*)((char*)d_ws + 393216 + 1048576);
  unsigned short* Vb = (unsigned short*)((char*)d_ws + 393216 + 2 * 1048576);

  wtrans_kernel<<<dim3(48), dim3(256), 0, stream>>>(Wq, Wk, Wv, Wt);
  qkv_kernel<<<dim3(256), dim3(256), 0, stream>>>(x, Wt, Bq, Bk, Bv, Qb, Kb, Vb);
  attn_kernel<<<dim3(256), dim3(128), 0, stream>>>(Qb, Kb, Vb, out);
}

// Round 2
// 74.882 us; speedup vs baseline: 1.5752x; 1.5752x over previous
//
#include <hip/hip_runtime.h>
#include <stdint.h>

#define NBATCH 4
#define NS 2048
#define ND 1024
#define NK 64
#define QSCALE 0.18033688011112042f  // 0.125 * log2(e), folded into Q

typedef __attribute__((ext_vector_type(4))) float f32x4;
typedef __attribute__((ext_vector_type(16))) float f32x16;
typedef __attribute__((ext_vector_type(8))) short bf16x8;
typedef unsigned short u16;
typedef unsigned int u32;

__device__ __forceinline__ u16 f2bf(float f) {
  union { float f; u32 u; } v; v.f = f;
  u32 u = v.u;
  u += 0x7FFFu + ((u >> 16) & 1u);   // RNE
  return (u16)(u >> 16);
}

__device__ __forceinline__ u32 pk2(float lo, float hi) {
  u32 r;
  asm("v_cvt_pk_bf16_f32 %0, %1, %2" : "=v"(r) : "v"(lo), "v"(hi));
  return r;
}

// ---------------------------------------------------------------------------
// Kernel 0: W ([1024][64] f32, x3) -> Wt [192][1024] bf16 (transposed).
// ---------------------------------------------------------------------------
__global__ __launch_bounds__(256) void wtrans_kernel(
    const float* __restrict__ Wq, const float* __restrict__ Wk,
    const float* __restrict__ Wv, u16* __restrict__ Wt) {
  __shared__ float tile[64][65];
  int blk = blockIdx.x;            // 48 blocks: 3 matrices x 16 d-tiles
  int m = blk >> 4, dt = blk & 15;
  const float* W = (m == 0) ? Wq : (m == 1) ? Wk : Wv;
  int d0 = dt * 64;
  int t = threadIdx.x;
#pragma unroll
  for (int i = 0; i < 16; i++) {
    int idx = t + 256 * i;
    int dd = idx >> 6, c = idx & 63;
    tile[dd][c] = W[(d0 + dd) * 64 + c];
  }
  __syncthreads();
#pragma unroll
  for (int i = 0; i < 16; i++) {
    int idx = t + 256 * i;
    int c = idx >> 6, dd = idx & 63;
    Wt[(m * 64 + c) * 1024 + d0 + dd] = f2bf(tile[dd][c]);
  }
}

// ---------------------------------------------------------------------------
// Kernel 1: QKV projection. 256 blocks x 512 thr (8 waves = 2 row-halves x 4
// col-quarters). Block = 32 rows x 192 cols. Register double-buffered loads,
// no LDS, no barriers. Writes Qb (pre-scaled), Kb row-major, Vt TRANSPOSED
// ([b][k=64][s=2048]) so attention needs no V transpose.
// ---------------------------------------------------------------------------
__global__ __launch_bounds__(512) void qkv_kernel(
    const float* __restrict__ x, const u16* __restrict__ Wt,
    const float* __restrict__ Bq, const float* __restrict__ Bk,
    const float* __restrict__ Bv, u16* __restrict__ Qb,
    u16* __restrict__ Kb, u16* __restrict__ Vt) {
  int w = threadIdx.x >> 6, lane = threadIdx.x & 63;
  int g = lane >> 4, c = lane & 15;
  int rh = w & 1, cq = w >> 1;
  long row = (long)blockIdx.x * 32 + rh * 16 + c;
  const float* xr = x + row * ND + g * 8;
  const u16* wbb = Wt + (cq * 48 + c) * ND + g * 8;

  f32x4 xa[2][4];
  bf16x8 wv[2][6];
#define LOADT(BUF, T) do {                                            \
    const float* xp_ = xr + (T) * 64;                                 \
    xa[BUF][0] = *(const f32x4*)(xp_);                                \
    xa[BUF][1] = *(const f32x4*)(xp_ + 4);                            \
    xa[BUF][2] = *(const f32x4*)(xp_ + 32);                           \
    xa[BUF][3] = *(const f32x4*)(xp_ + 36);                           \
    _Pragma("unroll")                                                 \
    for (int tt = 0; tt < 3; tt++) {                                  \
      wv[BUF][tt * 2]     = *(const bf16x8*)(wbb + tt * 16 * ND + (T) * 64); \
      wv[BUF][tt * 2 + 1] = *(const bf16x8*)(wbb + tt * 16 * ND + (T) * 64 + 32); \
    }                                                                 \
  } while (0)

  LOADT(0, 0);
  f32x4 acc[3];
#pragma unroll
  for (int tt = 0; tt < 3; tt++) acc[tt] = (f32x4){0.f, 0.f, 0.f, 0.f};

#pragma unroll
  for (int t = 0; t < 16; t++) {
    int cur = t & 1;
    if (t < 15) LOADT(cur ^ 1, t + 1);
    union { bf16x8 v; u16 u[8]; } af0, af1;
#pragma unroll
    for (int i = 0; i < 4; i++) {
      af0.u[i]     = f2bf(xa[cur][0][i]);
      af0.u[4 + i] = f2bf(xa[cur][1][i]);
      af1.u[i]     = f2bf(xa[cur][2][i]);
      af1.u[4 + i] = f2bf(xa[cur][3][i]);
    }
#pragma unroll
    for (int tt = 0; tt < 3; tt++) {
      acc[tt] = __builtin_amdgcn_mfma_f32_16x16x32_bf16(af0.v, wv[cur][tt * 2],     acc[tt], 0, 0, 0);
      acc[tt] = __builtin_amdgcn_mfma_f32_16x16x32_bf16(af1.v, wv[cur][tt * 2 + 1], acc[tt], 0, 0, 0);
    }
  }
#undef LOADT

  // epilogue: D row=(lane>>4)*4+j, col=lane&15
  long orow0 = (long)blockIdx.x * 32 + rh * 16 + 4 * g;
#pragma unroll
  for (int tt = 0; tt < 3; tt++) {
    int colg = cq * 48 + tt * 16 + c;
    int mtx = colg >> 6;                 // 0=Q 1=K 2=V (tiles never straddle)
    int col = colg & 63;
    const float* Bias = (mtx == 0) ? Bq : (mtx == 1) ? Bk : Bv;
#pragma unroll
    for (int j = 0; j < 4; j++) {
      long r = orow0 + j;
      int srow = (int)(r & (NS - 1));
      float v = acc[tt][j] + Bias[srow * NK + col];
      if (mtx == 0) {
        Qb[r * NK + col] = f2bf(v * QSCALE);
      } else if (mtx == 1) {
        Kb[r * NK + col] = f2bf(v);
      } else {
        int bb = (int)(r >> 11);
        Vt[((long)bb * NK + col) * NS + srow] = f2bf(v);
      }
    }
  }
}

// ---------------------------------------------------------------------------
// Kernel 2: flash attention, split-KV, zero LDS, 1 wave per block.
// 32x32x16 MFMA, swapped QK^T (S^T = K * Q^T) so each lane owns P for one
// q-row; no-max softmax (scores bounded, exp2 safe in f32); P packed to
// A-fragments in-register via cvt_pk + shfl_xor(32); V read pre-transposed.
// ---------------------------------------------------------------------------
__device__ __forceinline__ bf16x8 pack8(float p0, float p1, float p2, float p3,
                                        float p4, float p5, float p6, float p7,
                                        int hi) {
  u32 A = pk2(p0, p1), B = pk2(p2, p3), C = pk2(p4, p5), D = pk2(p6, p7);
  u32 sA = (u32)__shfl_xor((int)A, 32);
  u32 sB = (u32)__shfl_xor((int)B, 32);
  u32 sC = (u32)__shfl_xor((int)C, 32);
  u32 sD = (u32)__shfl_xor((int)D, 32);
  union { u32 w[4]; bf16x8 v; } u;
  u.w[0] = hi ? sC : A;
  u.w[1] = hi ? sD : B;
  u.w[2] = hi ? C : sA;
  u.w[3] = hi ? D : sB;
  return u.v;
}

__global__ __launch_bounds__(64, 2) void attn_kernel(
    const u16* __restrict__ Qb, const u16* __restrict__ Kb,
    const u16* __restrict__ Vt, float* __restrict__ Opart,
    float* __restrict__ lpart, int nsplit, int logsplit, int xgrp) {
  int lane = threadIdx.x;
  int q = lane & 31, hi = lane >> 5;
  int bid = blockIdx.x;
  int G, qt;
  if (nsplit == 1) { G = bid >> 6; qt = bid & 63; }
  else {                         // same-KV-chunk blocks share an XCD (bid%8)
    int xs = bid & 7, idx = bid >> 3;
    G = xs * xgrp + (idx >> 6);
    qt = idx & 63;
  }
  int b = G >> logsplit, sp = G & (nsplit - 1);
  int chunk = NS >> logsplit;
  int sb = sp * chunk;
  int steps = chunk >> 6;

  long qglob = (long)b * NS + qt * 32;
  bf16x8 qf[4];
  {
    const u16* qp = Qb + (qglob + q) * NK + hi * 8;
#pragma unroll
    for (int kk = 0; kk < 4; kk++) qf[kk] = *(const bf16x8*)(qp + kk * 16);
  }
  const u16* kbp = Kb + ((long)b * NS + sb + q) * NK + hi * 8;
  const u16* vbp = Vt + ((long)b * NK + q) * NS + sb + hi * 8;

  f32x16 o0, o1;
#pragma unroll
  for (int r = 0; r < 16; r++) { o0[r] = 0.f; o1[r] = 0.f; }
  float lacc[4] = {0.f, 0.f, 0.f, 0.f};

  bf16x8 kA0[4], kA1[4], kB0[4], kB1[4];
#pragma unroll
  for (int kk = 0; kk < 4; kk++) {             // prologue: K frags for t=0
    kA0[kk] = *(const bf16x8*)(kbp + kk * 16);
    kA1[kk] = *(const bf16x8*)(kbp + 32 * NK + kk * 16);
  }

#define ATTN_STEP(T, KC0, KC1, KN0, KN1)                                      \
  do {                                                                        \
    int t_ = (T);                                                             \
    const u16* vt_ = vbp + t_ * 64;                                           \
    bf16x8 vf0[4], vf1[4];                                                    \
    _Pragma("unroll") for (int s16 = 0; s16 < 4; s16++) {                     \
      vf0[s16] = *(const bf16x8*)(vt_ + s16 * 16);                            \
      vf1[s16] = *(const bf16x8*)(vt_ + 32 * NS + s16 * 16);                  \
    }                                                                         \
    f32x16 s0, s1;                                                            \
    _Pragma("unroll") for (int r = 0; r < 16; r++) { s0[r] = 0.f; s1[r] = 0.f; } \
    _Pragma("unroll") for (int kk = 0; kk < 4; kk++)                          \
      s0 = __builtin_amdgcn_mfma_f32_32x32x16_bf16(KC0[kk], qf[kk], s0, 0, 0, 0); \
    _Pragma("unroll") for (int kk = 0; kk < 4; kk++)                          \
      s1 = __builtin_amdgcn_mfma_f32_32x32x16_bf16(KC1[kk], qf[kk], s1, 0, 0, 0); \
    if (t_ + 1 < steps) {                                                     \
      const u16* kn_ = kbp + (long)(t_ + 1) * 64 * NK;                        \
      _Pragma("unroll") for (int kk = 0; kk < 4; kk++) {                      \
        KN0[kk] = *(const bf16x8*)(kn_ + kk * 16);                            \
        KN1[kk] = *(const bf16x8*)(kn_ + 32 * NK + kk * 16);                  \
      }                                                                       \
    }                                                                         \
    _Pragma("unroll") for (int r = 0; r < 16; r++) {                          \
      s0[r] = exp2f(s0[r]); s1[r] = exp2f(s1[r]);                             \
      lacc[r & 3] += s0[r] + s1[r];                                           \
    }                                                                         \
    bf16x8 pa[4];                                                             \
    pa[0] = pack8(s0[0], s0[1], s0[2], s0[3], s0[4], s0[5], s0[6], s0[7], hi);   \
    pa[1] = pack8(s0[8], s0[9], s0[10], s0[11], s0[12], s0[13], s0[14], s0[15], hi); \
    pa[2] = pack8(s1[0], s1[1], s1[2], s1[3], s1[4], s1[5], s1[6], s1[7], hi);   \
    pa[3] = pack8(s1[8], s1[9], s1[10], s1[11], s1[12], s1[13], s1[14], s1[15], hi); \
    _Pragma("unroll") for (int s16 = 0; s16 < 4; s16++) {                     \
      o0 = __builtin_amdgcn_mfma_f32_32x32x16_bf16(pa[s16], vf0[s16], o0, 0, 0, 0); \
      o1 = __builtin_amdgcn_mfma_f32_32x32x16_bf16(pa[s16], vf1[s16], o1, 0, 0, 0); \
    }                                                                         \
  } while (0)

  for (int t = 0; t < steps; t += 2) {
    ATTN_STEP(t,     kA0, kA1, kB0, kB1);
    ATTN_STEP(t + 1, kB0, kB1, kA0, kA1);
  }
#undef ATTN_STEP

  float lt = (lacc[0] + lacc[1]) + (lacc[2] + lacc[3]);
  lt += __shfl_xor(lt, 32);

  if (nsplit == 1) {
    float inv = 1.0f / lt;
#pragma unroll
    for (int r = 0; r < 16; r++) {
      int qq = (r & 3) + 8 * (r >> 2) + 4 * hi;
      float* op = Opart + (qglob + qq) * NK + q;
      op[0]  = o0[r] * inv;
      op[32] = o1[r] * inv;
    }
  } else {
    long ob = (long)sp * (NBATCH * NS * NK);
#pragma unroll
    for (int r = 0; r < 16; r++) {
      int qq = (r & 3) + 8 * (r >> 2) + 4 * hi;
      float* op = Opart + ob + (qglob + qq) * NK + q;
      op[0]  = o0[r];
      op[32] = o1[r];
    }
    if (hi == 0) lpart[sp * (NBATCH * NS) + qglob + q] = lt;
  }
}

// ---------------------------------------------------------------------------
// Kernel 3: combine split-KV partials (sum of unnormalized O and l).
// ---------------------------------------------------------------------------
__global__ __launch_bounds__(256) void combine_kernel(
    const float* __restrict__ Opart, const float* __restrict__ lpart,
    float* __restrict__ out, int nsplit) {
  int gid = blockIdx.x * 256 + threadIdx.x;     // 131072 = 8192 rows * 16
  int rw = gid >> 4, c4 = (gid & 15) * 4;
  f32x4 a = (f32x4){0.f, 0.f, 0.f, 0.f};
  float l = 0.f;
  for (int sp = 0; sp < nsplit; sp++) {
    a += *(const f32x4*)(Opart + (long)sp * (NBATCH * NS * NK) + (long)rw * NK + c4);
    l += lpart[sp * (NBATCH * NS) + rw];
  }
  float inv = 1.0f / l;
  f32x4 r;
#pragma unroll
  for (int i = 0; i < 4; i++) r[i] = a[i] * inv;
  *(f32x4*)(out + (long)rw * NK + c4) = r;
}

// ---------------------------------------------------------------------------
extern "C" void kernel_launch(void* const* d_in, const int* in_sizes, int n_in,
                              void* d_out, int out_size, void* d_ws, size_t ws_size,
                              hipStream_t stream) {
  const float* x  = (const float*)d_in[0];
  const float* Wq = (const float*)d_in[1];
  const float* Bq = (const float*)d_in[2];
  const float* Wk = (const float*)d_in[3];
  const float* Bk = (const float*)d_in[4];
  const float* Wv = (const float*)d_in[5];
  const float* Bv = (const float*)d_in[6];
  float* out = (float*)d_out;

  char* ws = (char*)d_ws;
  u16* Wt = (u16*)ws;                         // 393216 B
  u16* Qb = (u16*)(ws + 393216);              // 1 MB
  u16* Kb = (u16*)(ws + 1441792);             // 1 MB
  u16* Vt = (u16*)(ws + 2490368);             // 1 MB (transposed V)
  float* lpart = (float*)(ws + 3538944);      // up to 256 KB
  float* Opart = (float*)(ws + 3801088);      // split * 2 MB

  int split = 8;
  while (split > 1 && (size_t)(3801088) + (size_t)split * 2097152 > ws_size)
    split >>= 1;
  int logsplit = (split == 8) ? 3 : (split == 4) ? 2 : (split == 2) ? 1 : 0;

  wtrans_kernel<<<dim3(48), dim3(256), 0, stream>>>(Wq, Wk, Wv, Wt);
  qkv_kernel<<<dim3(256), dim3(512), 0, stream>>>(x, Wt, Bq, Bk, Bv, Qb, Kb, Vt);

  float* Odst = (split == 1) ? out : Opart;
  attn_kernel<<<dim3(256 * split), dim3(64), 0, stream>>>(
      Qb, Kb, Vt, Odst, lpart, split, logsplit, split / 2);
  if (split > 1)
    combine_kernel<<<dim3(512), dim3(256), 0, stream>>>(Opart, lpart, out, split);
}

// Round 3
// 69.233 us; speedup vs baseline: 1.7037x; 1.0816x over previous
//
#include <hip/hip_runtime.h>
#include <stdint.h>

#define NBATCH 4
#define NS 2048
#define ND 1024
#define NK 64
#define QSCALE 0.18033688011112042f  // 0.125 * log2(e), folded into Q

typedef __attribute__((ext_vector_type(4))) float f32x4;
typedef __attribute__((ext_vector_type(16))) float f32x16;
typedef __attribute__((ext_vector_type(8))) short bf16x8;
typedef unsigned short u16;
typedef unsigned int u32;

__device__ __forceinline__ u16 f2bf(float f) {
  union { float f; u32 u; } v; v.f = f;
  u32 u = v.u;
  u += 0x7FFFu + ((u >> 16) & 1u);   // RNE
  return (u16)(u >> 16);
}

__device__ __forceinline__ u32 pk2(float lo, float hi) {
  u32 r;
  asm("v_cvt_pk_bf16_f32 %0, %1, %2" : "=v"(r) : "v"(lo), "v"(hi));
  return r;
}

// ---------------------------------------------------------------------------
// Kernel 0: W ([1024][64] f32, x3) -> Wt [192][1024] bf16 (transposed).
// ---------------------------------------------------------------------------
__global__ __launch_bounds__(256) void wtrans_kernel(
    const float* __restrict__ Wq, const float* __restrict__ Wk,
    const float* __restrict__ Wv, u16* __restrict__ Wt) {
  __shared__ float tile[64][65];
  int blk = blockIdx.x;            // 48 blocks: 3 matrices x 16 d-tiles
  int m = blk >> 4, dt = blk & 15;
  const float* W = (m == 0) ? Wq : (m == 1) ? Wk : Wv;
  int d0 = dt * 64;
  int t = threadIdx.x;
#pragma unroll
  for (int i = 0; i < 16; i++) {
    int idx = t + 256 * i;
    int dd = idx >> 6, c = idx & 63;
    tile[dd][c] = W[(d0 + dd) * 64 + c];
  }
  __syncthreads();
#pragma unroll
  for (int i = 0; i < 16; i++) {
    int idx = t + 256 * i;
    int c = idx >> 6, dd = idx & 63;
    Wt[(m * 64 + c) * 1024 + d0 + dd] = f2bf(tile[dd][c]);
  }
}

// ---------------------------------------------------------------------------
// Kernel 1: QKV projection. 256 blocks x 512 thr (8 waves = 2 row-halves x 4
// col-quarters). Block = 32 rows x 192 cols, full K=1024. 3-deep register
// prefetch (~20 loads in flight/wave); launch_bounds(512,2) gives the
// allocator a 256-VGPR budget so the buffers actually live in registers
// (R2's 32-VGPR allocation serialized all loads). No LDS, no barriers.
// Writes Qb (pre-scaled by 0.125*log2e), Kb row-major, Vt transposed.
// ---------------------------------------------------------------------------
__global__ __launch_bounds__(512, 2) void qkv_kernel(
    const float* __restrict__ x, const u16* __restrict__ Wt,
    const float* __restrict__ Bq, const float* __restrict__ Bk,
    const float* __restrict__ Bv, u16* __restrict__ Qb,
    u16* __restrict__ Kb, u16* __restrict__ Vt) {
  int w = threadIdx.x >> 6, lane = threadIdx.x & 63;
  int g = lane >> 4, c = lane & 15;
  int rh = w & 1, cq = w >> 1;
  long row = (long)blockIdx.x * 32 + rh * 16 + c;
  const float* xr = x + row * ND + g * 8;
  const u16* wbb = Wt + (cq * 48 + c) * ND + g * 8;

  f32x4 xa[3][4];
  bf16x8 wv[3][6];
#define LOADT(BUF, T) do {                                            \
    const float* xp_ = xr + (T) * 64;                                 \
    xa[BUF][0] = *(const f32x4*)(xp_);                                \
    xa[BUF][1] = *(const f32x4*)(xp_ + 4);                            \
    xa[BUF][2] = *(const f32x4*)(xp_ + 32);                           \
    xa[BUF][3] = *(const f32x4*)(xp_ + 36);                           \
    _Pragma("unroll")                                                 \
    for (int tt = 0; tt < 3; tt++) {                                  \
      wv[BUF][tt * 2]     = *(const bf16x8*)(wbb + tt * 16 * ND + (T) * 64); \
      wv[BUF][tt * 2 + 1] = *(const bf16x8*)(wbb + tt * 16 * ND + (T) * 64 + 32); \
    }                                                                 \
  } while (0)

  LOADT(0, 0);
  LOADT(1, 1);
  f32x4 acc[3];
#pragma unroll
  for (int tt = 0; tt < 3; tt++) acc[tt] = (f32x4){0.f, 0.f, 0.f, 0.f};

#pragma unroll
  for (int t = 0; t < 16; t++) {
    int cur = t % 3;
    if (t < 14) LOADT((t + 2) % 3, t + 2);
    union { bf16x8 v; u32 w[4]; } af0, af1;
    af0.w[0] = pk2(xa[cur][0][0], xa[cur][0][1]);
    af0.w[1] = pk2(xa[cur][0][2], xa[cur][0][3]);
    af0.w[2] = pk2(xa[cur][1][0], xa[cur][1][1]);
    af0.w[3] = pk2(xa[cur][1][2], xa[cur][1][3]);
    af1.w[0] = pk2(xa[cur][2][0], xa[cur][2][1]);
    af1.w[1] = pk2(xa[cur][2][2], xa[cur][2][3]);
    af1.w[2] = pk2(xa[cur][3][0], xa[cur][3][1]);
    af1.w[3] = pk2(xa[cur][3][2], xa[cur][3][3]);
#pragma unroll
    for (int tt = 0; tt < 3; tt++) {
      acc[tt] = __builtin_amdgcn_mfma_f32_16x16x32_bf16(af0.v, wv[cur][tt * 2],     acc[tt], 0, 0, 0);
      acc[tt] = __builtin_amdgcn_mfma_f32_16x16x32_bf16(af1.v, wv[cur][tt * 2 + 1], acc[tt], 0, 0, 0);
    }
  }
#undef LOADT

  // epilogue: D row=(lane>>4)*4+j, col=lane&15
  long orow0 = (long)blockIdx.x * 32 + rh * 16 + 4 * g;
#pragma unroll
  for (int tt = 0; tt < 3; tt++) {
    int colg = cq * 48 + tt * 16 + c;
    int mtx = colg >> 6;                 // 0=Q 1=K 2=V (wave-uniform)
    int col = colg & 63;
    const float* Bias = (mtx == 0) ? Bq : (mtx == 1) ? Bk : Bv;
#pragma unroll
    for (int j = 0; j < 4; j++) {
      long r = orow0 + j;
      int srow = (int)(r & (NS - 1));
      float v = acc[tt][j] + Bias[srow * NK + col];
      if (mtx == 0) {
        Qb[r * NK + col] = f2bf(v * QSCALE);
      } else if (mtx == 1) {
        Kb[r * NK + col] = f2bf(v);
      } else {
        int bb = (int)(r >> 11);
        Vt[((long)bb * NK + col) * NS + srow] = f2bf(v);
      }
    }
  }
}

// ---------------------------------------------------------------------------
// Kernel 2: flash attention, in-block KV split, LDS merge, no extra ws.
// 256 blocks (b,qt XCD-swizzled: batch b owns XCDs {2b,2b+1}) x 8 waves.
// Wave w handles KV rows [w*256,(w+1)*256) of its q-tile: 4 steps of 64.
// Swapped QK^T (S^T = K*Q^T, lane owns one q-row), no-max exp2 softmax,
// in-register P pack (cvt_pk + shfl_xor32), V read pre-transposed.
// Merge: l and unnormalized O are pure sums across waves -> LDS tree.
// ---------------------------------------------------------------------------
__device__ __forceinline__ bf16x8 pack8(float p0, float p1, float p2, float p3,
                                        float p4, float p5, float p6, float p7,
                                        int hi) {
  u32 A = pk2(p0, p1), B = pk2(p2, p3), C = pk2(p4, p5), D = pk2(p6, p7);
  u32 sA = (u32)__shfl_xor((int)A, 32);
  u32 sB = (u32)__shfl_xor((int)B, 32);
  u32 sC = (u32)__shfl_xor((int)C, 32);
  u32 sD = (u32)__shfl_xor((int)D, 32);
  union { u32 w[4]; bf16x8 v; } u;
  u.w[0] = hi ? sC : A;
  u.w[1] = hi ? sD : B;
  u.w[2] = hi ? C : sA;
  u.w[3] = hi ? D : sB;
  return u.v;
}

__global__ __launch_bounds__(512, 1) void attn_kernel(
    const u16* __restrict__ Qb, const u16* __restrict__ Kb,
    const u16* __restrict__ Vt, float* __restrict__ out) {
  __shared__ float Ol[8][32][64];
  __shared__ float Ll[8][32];
  int w = threadIdx.x >> 6, lane = threadIdx.x & 63;
  int q = lane & 31, hi = lane >> 5;
  int bid = blockIdx.x;
  int b = (bid & 7) >> 1;                      // batch b on XCDs {2b,2b+1}
  int qt = ((bid >> 3) << 1) | (bid & 1);
  long qglob = (long)b * NS + qt * 32;

  bf16x8 qf[4];
  {
    const u16* qp = Qb + (qglob + q) * NK + hi * 8;
#pragma unroll
    for (int kk = 0; kk < 4; kk++) qf[kk] = *(const bf16x8*)(qp + kk * 16);
  }
  int sb = w * 256;
  const u16* kbp = Kb + ((long)b * NS + sb + q) * NK + hi * 8;
  const u16* vbp = Vt + ((long)b * NK + q) * NS + sb + hi * 8;

  f32x16 o0, o1;
#pragma unroll
  for (int r = 0; r < 16; r++) { o0[r] = 0.f; o1[r] = 0.f; }
  float lacc[4] = {0.f, 0.f, 0.f, 0.f};

  bf16x8 kA0[4], kA1[4], kB0[4], kB1[4];
#pragma unroll
  for (int kk = 0; kk < 4; kk++) {             // prologue: K frags for t=0
    kA0[kk] = *(const bf16x8*)(kbp + kk * 16);
    kA1[kk] = *(const bf16x8*)(kbp + 32 * NK + kk * 16);
  }

#define ATTN_STEP(T, KC0, KC1, KN0, KN1)                                      \
  do {                                                                        \
    int t_ = (T);                                                             \
    const u16* vt_ = vbp + t_ * 64;                                           \
    bf16x8 vf0[4], vf1[4];                                                    \
    _Pragma("unroll") for (int i = 0; i < 4; i++) {                           \
      vf0[i] = *(const bf16x8*)(vt_ + i * 16);                                \
      vf1[i] = *(const bf16x8*)(vt_ + 32 * NS + i * 16);                      \
    }                                                                         \
    if (t_ + 1 < 4) {                                                         \
      const u16* kn_ = kbp + (long)(t_ + 1) * 64 * NK;                        \
      _Pragma("unroll") for (int i = 0; i < 4; i++) {                         \
        KN0[i] = *(const bf16x8*)(kn_ + i * 16);                              \
        KN1[i] = *(const bf16x8*)(kn_ + 32 * NK + i * 16);                    \
      }                                                                       \
    }                                                                         \
    f32x16 s0, s1;                                                            \
    _Pragma("unroll") for (int r = 0; r < 16; r++) { s0[r] = 0.f; s1[r] = 0.f; } \
    _Pragma("unroll") for (int i = 0; i < 4; i++)                             \
      s0 = __builtin_amdgcn_mfma_f32_32x32x16_bf16(KC0[i], qf[i], s0, 0, 0, 0); \
    _Pragma("unroll") for (int i = 0; i < 4; i++)                             \
      s1 = __builtin_amdgcn_mfma_f32_32x32x16_bf16(KC1[i], qf[i], s1, 0, 0, 0); \
    _Pragma("unroll") for (int r = 0; r < 16; r++) {                          \
      s0[r] = exp2f(s0[r]); s1[r] = exp2f(s1[r]);                             \
      lacc[r & 3] += s0[r] + s1[r];                                           \
    }                                                                         \
    bf16x8 pa[4];                                                             \
    pa[0] = pack8(s0[0], s0[1], s0[2], s0[3], s0[4], s0[5], s0[6], s0[7], hi);   \
    pa[1] = pack8(s0[8], s0[9], s0[10], s0[11], s0[12], s0[13], s0[14], s0[15], hi); \
    pa[2] = pack8(s1[0], s1[1], s1[2], s1[3], s1[4], s1[5], s1[6], s1[7], hi);   \
    pa[3] = pack8(s1[8], s1[9], s1[10], s1[11], s1[12], s1[13], s1[14], s1[15], hi); \
    _Pragma("unroll") for (int i = 0; i < 4; i++) {                           \
      o0 = __builtin_amdgcn_mfma_f32_32x32x16_bf16(pa[i], vf0[i], o0, 0, 0, 0); \
      o1 = __builtin_amdgcn_mfma_f32_32x32x16_bf16(pa[i], vf1[i], o1, 0, 0, 0); \
    }                                                                         \
  } while (0)

  ATTN_STEP(0, kA0, kA1, kB0, kB1);
  ATTN_STEP(1, kB0, kB1, kA0, kA1);
  ATTN_STEP(2, kA0, kA1, kB0, kB1);
  ATTN_STEP(3, kB0, kB1, kA0, kA1);
#undef ATTN_STEP

  float lt = (lacc[0] + lacc[1]) + (lacc[2] + lacc[3]);
  lt += __shfl_xor(lt, 32);

  // stage per-wave partials (D row = (r&3)+8*(r>>2)+4*hi = q-row; col = k)
#pragma unroll
  for (int r = 0; r < 16; r++) {
    int qq = (r & 3) + 8 * (r >> 2) + 4 * hi;
    Ol[w][qq][q]      = o0[r];
    Ol[w][qq][q + 32] = o1[r];
  }
  if (hi == 0) Ll[w][q] = lt;
  __syncthreads();

  // tree reduce across waves: 4, 2, 1
#pragma unroll
  for (int rr = 4; rr >= 1; rr >>= 1) {
    if (w < rr) {
#pragma unroll
      for (int i = 0; i < 8; i++) {
        int idx = lane + i * 64;               // 0..511 over 2048 f32 (x4)
        f32x4* dst = (f32x4*)&Ol[w][idx >> 4][(idx & 15) * 4];
        const f32x4* src = (const f32x4*)&Ol[w + rr][idx >> 4][(idx & 15) * 4];
        *dst += *src;
      }
      if (lane < 32) Ll[w][lane] += Ll[w + rr][lane];
    }
    __syncthreads();
  }

  // normalize + store: 512 threads x 1 f32x4 = 32 rows x 64 cols
  {
    int idx = threadIdx.x;
    int row = idx >> 4, c4 = (idx & 15) * 4;
    float inv = 1.0f / Ll[0][row];
    f32x4 v = *(const f32x4*)&Ol[0][row][c4];
    f32x4 r;
#pragma unroll
    for (int i = 0; i < 4; i++) r[i] = v[i] * inv;
    *(f32x4*)&out[(qglob + row) * NK + c4] = r;
  }
}

// ---------------------------------------------------------------------------
extern "C" void kernel_launch(void* const* d_in, const int* in_sizes, int n_in,
                              void* d_out, int out_size, void* d_ws, size_t ws_size,
                              hipStream_t stream) {
  const float* x  = (const float*)d_in[0];
  const float* Wq = (const float*)d_in[1];
  const float* Bq = (const float*)d_in[2];
  const float* Wk = (const float*)d_in[3];
  const float* Bk = (const float*)d_in[4];
  const float* Wv = (const float*)d_in[5];
  const float* Bv = (const float*)d_in[6];
  float* out = (float*)d_out;

  char* ws = (char*)d_ws;
  u16* Wt = (u16*)ws;                         // 384 KB
  u16* Qb = (u16*)(ws + 393216);              // 1 MB
  u16* Kb = (u16*)(ws + 1441792);             // 1 MB
  u16* Vt = (u16*)(ws + 2490368);             // 1 MB (transposed V)

  wtrans_kernel<<<dim3(48), dim3(256), 0, stream>>>(Wq, Wk, Wv, Wt);
  qkv_kernel<<<dim3(256), dim3(512), 0, stream>>>(x, Wt, Bq, Bk, Bv, Qb, Kb, Vt);
  attn_kernel<<<dim3(256), dim3(512), 0, stream>>>(Qb, Kb, Vt, out);
}